// Round 13
// baseline (124.551 us; speedup 1.0000x reference)
//
#include <hip/hip_runtime.h>
#include <hip/hip_bf16.h>
#include <math.h>

#define BATCH_N 8192
#define K_DIM   2048
#define CLS     1000

typedef __attribute__((ext_vector_type(8))) short short8;
typedef __attribute__((ext_vector_type(8))) unsigned short ushort8;
typedef __attribute__((ext_vector_type(4))) float floatx4;

static __device__ __forceinline__ float softplus_fast(float z) {
    return fmaxf(z, 0.f) + __logf(1.f + __expf(-fabsf(z)));
}

static __device__ __forceinline__ ushort f2bfr(float f) {
    return __hip_bfloat16_raw(__float2bfloat16(f)).x;
}

#define BARX  __builtin_amdgcn_s_barrier()
#define LGKM0 asm volatile("s_waitcnt lgkmcnt(0)" ::: "memory")
#define SB0   __builtin_amdgcn_sched_barrier(0)
#define PRIO1 __builtin_amdgcn_s_setprio(1)
#define PRIO0 __builtin_amdgcn_s_setprio(0)

constexpr int NT = K_DIM / 32;   // 64 K-tiles

// ---- 256x128 GEMM, fused fp32->bf16 staging, BK=32, 2-slot dbuf, 1 bar/tile
// Round-12 per-wave geometry (64x64 out, acc=64) but 512-thread blocks:
// 2 blocks/CU RESIDENT (LDS 48KB x2 = 96 <= 160; ~128 unified regs/wave x 16
// waves/CU) => two INDEPENDENT 8-wave barrier groups per CU — while one
// block drains lgkm+barrier, the other issues MFMA (m114 mechanism at the
// correct register footprint; r8's forced-cap and r9's tiny-tile avoided).
// 8 waves = 4(wr) x 2(wc). Slot layout (verified, 0 bank conflicts):
// 16B chunk q: p=q>>3, c8l=(q&7)^(p&7), row=2p+(c8l>>2), k=(c8l&3)*8.
// Staging: reg-load fp32 -> cvt -> swizzled ds_write_b128; NO vmcnt at the
// barrier (global loads feed only the loading thread's own cvt).

__global__ __launch_bounds__(512, 2)
void gemm_fused(const float* __restrict__ Xa, const float* __restrict__ Xb,
                const float* __restrict__ Wa, const float* __restrict__ Wb,
                const float* __restrict__ biasa, const float* __restrict__ biasb,
                float* __restrict__ outa, float* __restrict__ outb)
{
    // bijective XCD swizzle over the 512-block grid (512 % 8 == 0)
    int flat = blockIdx.x + 8 * (blockIdx.y + 32 * blockIdx.z);
    int sw   = (flat & 7) * 64 + (flat >> 3);
    const int bx = sw & 7, by = (sw >> 3) & 31, bz = sw >> 8;

    const float* A    = bz ? Xb : Xa;       // [8192][2048] fp32
    const float* B    = bz ? Wb : Wa;       // [1000][2048] fp32
    const float* bias = bz ? biasb : biasa;
    float* out        = bz ? outb : outa;

    __shared__ ushort As[2][256 * 32];      // 16 KiB per slot
    __shared__ ushort Bs[2][128 * 32];      // 8 KiB per slot  (48 KiB total)

    const int tid  = threadIdx.x;
    const int lane = tid & 63;
    const int wid  = tid >> 6;              // 8 waves: wr in {0..3}, wc in {0,1}
    const int wr = wid >> 1, wc = wid & 1;
    const int fr = lane & 15, fg = lane >> 4;
    const int brow = by * 256;
    const int bcol = bx * 128;

    // staging map: A = 1024 chunks (2/thread), B = 512 chunks (1/thread)
    size_t a_g[2], b_g;
    int    a_l[2], b_l;
#pragma unroll
    for (int i = 0; i < 2; ++i) {
        int q = tid + i * 512;
        int p = q >> 3, c8 = q & 7, c8l = c8 ^ (p & 7);
        int r = 2 * p + (c8l >> 2);
        a_g[i] = (size_t)(brow + r) * K_DIM + (c8l & 3) * 8;
        a_l[i] = q * 8;
    }
    {
        int q = tid;
        int p = q >> 3, c8 = q & 7, c8l = c8 ^ (p & 7);
        int r = 2 * p + (c8l >> 2);
        int wrow = bcol + r; if (wrow >= CLS) wrow = CLS - 1;   // clamp pad
        b_g = (size_t)wrow * K_DIM + (c8l & 3) * 8;
        b_l = q * 8;
    }

    // fragment-read offsets (verified layout); per-wave 64x64 output
    int afoff[4], bfoff[4];
#pragma unroll
    for (int m = 0; m < 4; ++m) {
        int row = wr * 64 + m * 16 + fr;
        int p = row >> 1;
        int c = (((row & 1) << 2) | fg) ^ (p & 7);
        afoff[m] = (p * 8 + c) * 8;
    }
#pragma unroll
    for (int n = 0; n < 4; ++n) {
        int row = wc * 64 + n * 16 + fr;
        int p = row >> 1;
        int c = (((row & 1) << 2) | fg) ^ (p & 7);
        bfoff[n] = (p * 8 + c) * 8;
    }

    floatx4 acc[4][4];
#pragma unroll
    for (int m = 0; m < 4; ++m)
#pragma unroll
        for (int n = 0; n < 4; ++n)
            acc[m][n] = (floatx4){0.f, 0.f, 0.f, 0.f};

    float4 ga[2][2], gb[2];                 // staged fp32 (tile in flight)

#define LOADT(t_) {                                                           \
    const size_t kb_ = (size_t)(t_) * 32;                                     \
    ga[0][0] = *(const float4*)(A + a_g[0] + kb_);                            \
    ga[0][1] = *(const float4*)(A + a_g[0] + kb_ + 4);                        \
    ga[1][0] = *(const float4*)(A + a_g[1] + kb_);                            \
    ga[1][1] = *(const float4*)(A + a_g[1] + kb_ + 4);                        \
    gb[0]    = *(const float4*)(B + b_g + kb_);                               \
    gb[1]    = *(const float4*)(B + b_g + kb_ + 4);                           \
}

#define CVTW(sl_) {                                                           \
    _Pragma("unroll")                                                         \
    for (int i = 0; i < 2; ++i) {                                             \
        ushort8 ta;                                                           \
        _Pragma("unroll")                                                     \
        for (int j = 0; j < 4; ++j) {                                         \
            ta[j]     = f2bfr(((const float*)&ga[i][0])[j]);                  \
            ta[j + 4] = f2bfr(((const float*)&ga[i][1])[j]);                  \
        }                                                                     \
        *(ushort8*)&As[sl_][a_l[i]] = ta;                                     \
    }                                                                         \
    ushort8 tb;                                                               \
    _Pragma("unroll")                                                         \
    for (int j = 0; j < 4; ++j) {                                             \
        tb[j]     = f2bfr(((const float*)&gb[0])[j]);                         \
        tb[j + 4] = f2bfr(((const float*)&gb[1])[j]);                         \
    }                                                                         \
    *(ushort8*)&Bs[sl_][b_l] = tb;                                            \
}

    // prologue: tile 0 staged to slot 0; tile 1 loads in flight
    LOADT(0)
    CVTW(0)
    LOADT(1)
    SB0; LGKM0; BARX; SB0;

#pragma unroll 1
    for (int t = 0; t < NT; ++t) {
        const ushort* asl = &As[t & 1][0];
        const ushort* bsl = &Bs[t & 1][0];
        short8 af[4], bf[4];
#pragma unroll
        for (int m = 0; m < 4; ++m) af[m] = *(const short8*)(asl + afoff[m]);
#pragma unroll
        for (int n = 0; n < 4; ++n) bf[n] = *(const short8*)(bsl + bfoff[n]);

        PRIO1;
#pragma unroll
        for (int m = 0; m < 4; ++m)
#pragma unroll
            for (int n = 0; n < 4; ++n)
                acc[m][n] = __builtin_amdgcn_mfma_f32_16x16x32_bf16(
                    af[m], bf[n], acc[m][n], 0, 0, 0);
        PRIO0;

        if (t + 1 < NT) CVTW((t + 1) & 1)       // consumes loads of tile t+1
        if (t + 2 < NT) LOADT(t + 2)            // issue early; used next iter
        SB0; LGKM0; BARX; SB0;                  // NO vmcnt drain
    }

    // epilogue: alpha = softplus(z + bias) + 1, predicated on col < 1000
#pragma unroll
    for (int n = 0; n < 4; ++n) {
        int col = bcol + wc * 64 + n * 16 + fr;
        if (col >= CLS) continue;
        float bv = bias[col];
#pragma unroll
        for (int m = 0; m < 4; ++m) {
#pragma unroll
            for (int j = 0; j < 4; ++j) {
                int row = brow + wr * 64 + m * 16 + fg * 4 + j;
                float z = acc[m][n][j] + bv;
                out[(size_t)row * CLS + col] = softplus_fast(z) + 1.f;
            }
        }
    }
}

// ---------------- DS combine: one wave per row, shuffle-xor reduce ----------

__global__ __launch_bounds__(256)
void ds_combine(const float* __restrict__ AX, const float* __restrict__ AY,
                float* __restrict__ out)
{
    const int row = blockIdx.x * 4 + (threadIdx.x >> 6);
    const int l = threadIdx.x & 63;
    const float* ax = AX + (size_t)row * CLS;
    const float* ay = AY + (size_t)row * CLS;

    float4 vx[4], vy[4];
    float sx = 0.f, sy = 0.f, sp = 0.f;
#pragma unroll
    for (int c = 0; c < 4; ++c) {
        int idx = l + c * 64;
        if (idx < CLS / 4) {
            vx[c] = *(const float4*)(ax + idx * 4);
            vy[c] = *(const float4*)(ay + idx * 4);
            const float* px = (const float*)&vx[c];
            const float* py = (const float*)&vy[c];
#pragma unroll
            for (int j = 0; j < 4; ++j) {
                sx += px[j]; sy += py[j];
                sp += (px[j] - 1.f) * (py[j] - 1.f);
            }
        }
    }
#pragma unroll
    for (int off = 1; off < 64; off <<= 1) {
        sx += __shfl_xor(sx, off);
        sy += __shfl_xor(sy, off);
        sp += __shfl_xor(sp, off);
    }
    const float S1 = sx, S2 = sy, P = sp;
    const float i1 = 1.f / S1, i2 = 1.f / S2;
    const float u1 = (float)CLS * i1, u2 = (float)CLS * i2;
    const float sb1 = (S1 - (float)CLS) * i1;
    const float sb2 = (S2 - (float)CLS) * i2;
    const float conf = sb1 * sb2 - P * i1 * i2;
    const float denom = 1.f - conf;
    const float idenom = 1.f / denom;
    const float Sa = (float)CLS * denom / (u1 * u2);

#pragma unroll
    for (int c = 0; c < 4; ++c) {
        int idx = l + c * 64;
        if (idx < CLS / 4) {
            float4 vo;
            const float* px = (const float*)&vx[c];
            const float* py = (const float*)&vy[c];
            float* po = (float*)&vo;
#pragma unroll
            for (int j = 0; j < 4; ++j) {
                float b1 = (px[j] - 1.f) * i1;
                float b2 = (py[j] - 1.f) * i2;
                float ba = (b1 * b2 + b1 * u2 + b2 * u1) * idenom;
                po[j] = ba * Sa + 1.f;
            }
            *(float4*)(out + (size_t)row * CLS + idx * 4) = vo;
        }
    }
}

extern "C" void kernel_launch(void* const* d_in, const int* in_sizes, int n_in,
                              void* d_out, int out_size, void* d_ws, size_t ws_size,
                              hipStream_t stream) {
    const float* x  = (const float*)d_in[0];
    const float* y  = (const float*)d_in[1];
    const float* Wx = (const float*)d_in[2];
    const float* bx = (const float*)d_in[3];
    const float* Wy = (const float*)d_in[4];
    const float* by = (const float*)d_in[5];
    float* out = (float*)d_out;
    float* ax = out + (size_t)BATCH_N * CLS;
    float* ay = ax  + (size_t)BATCH_N * CLS;

    gemm_fused<<<dim3(8, 32, 2), 512, 0, stream>>>(
        x, y, Wx, Wy, bx, by, ax, ay);
    ds_combine<<<BATCH_N / 4, 256, 0, stream>>>(ax, ay, out);
}

// Round 14
// 118.948 us; speedup vs baseline: 1.0471x; 1.0471x over previous
//
#include <hip/hip_runtime.h>
#include <hip/hip_bf16.h>
#include <math.h>

#define BATCH_N 8192
#define K_DIM   2048
#define CLS     1000

typedef __attribute__((ext_vector_type(8))) short short8;
typedef __attribute__((ext_vector_type(8))) unsigned short ushort8;
typedef __attribute__((ext_vector_type(4))) float floatx4;

static __device__ __forceinline__ float softplus_fast(float z) {
    return fmaxf(z, 0.f) + __logf(1.f + __expf(-fabsf(z)));
}

static __device__ __forceinline__ ushort f2bfr(float f) {
    return __hip_bfloat16_raw(__float2bfloat16(f)).x;
}

#define BARX  __builtin_amdgcn_s_barrier()
#define LGKM0 asm volatile("s_waitcnt lgkmcnt(0)" ::: "memory")
#define SB0   __builtin_amdgcn_sched_barrier(0)
#define PRIO1 __builtin_amdgcn_s_setprio(1)
#define PRIO0 __builtin_amdgcn_s_setprio(0)

constexpr int NT = K_DIM / 32;   // 64 BK=32 tiles, 32 barrier windows

// ---- 256x256 GEMM, fused fp32->bf16 staging, 16 waves (r12), 4 rotating
// LDS slots, ONE barrier per TWO tiles. r12 kernel otherwise unchanged.
// 16 waves (4 wr x 4 wc), per-wave 64x64 out, acc=64 AGPR, ~64 VGPR =>
// 4 waves/SIMD resident (16 waves/CU) — the r12 occupancy win, now with
// half the barrier/drain sequences (the r11 lever, untested at this
// occupancy until now — regime-gate lesson).
// Slot layout (verified, 0 bank conflicts): 16B chunk q: p=q>>3,
// c8l=(q&7)^(p&7), row=2p+(c8l>>2), k=(c8l&3)*8.
// Race ledger: window s computes tiles {2s,2s+1} (slots (2s)&3,(2s+1)&3),
// writes slots (2s+2)&3,(2s+3)&3 — disjoint. Writes drained by the single
// lgkm0 before the barrier; WAR on a slot is one barrier after its last
// read (previous window's reads complete before that barrier).

__global__ __launch_bounds__(1024, 2)
void gemm_fused(const float* __restrict__ Xa, const float* __restrict__ Xb,
                const float* __restrict__ Wa, const float* __restrict__ Wb,
                const float* __restrict__ biasa, const float* __restrict__ biasb,
                float* __restrict__ outa, float* __restrict__ outb)
{
    // bijective XCD swizzle over the 256-block grid (256 % 8 == 0)
    int flat = blockIdx.x + 4 * (blockIdx.y + 32 * blockIdx.z);
    int sw   = (flat & 7) * 32 + (flat >> 3);
    const int bx = sw & 3, by = (sw >> 2) & 31, bz = sw >> 7;

    const float* A    = bz ? Xb : Xa;       // [8192][2048] fp32
    const float* B    = bz ? Wb : Wa;       // [1000][2048] fp32
    const float* bias = bz ? biasb : biasa;
    float* out        = bz ? outb : outa;

    __shared__ ushort As[4][256 * 32];      // 4 x 16 KiB
    __shared__ ushort Bs[4][256 * 32];      // total 128 KiB

    const int tid  = threadIdx.x;
    const int lane = tid & 63;
    const int wid  = tid >> 6;              // 16 waves: wr, wc in {0..3}
    const int wr = wid >> 2, wc = wid & 3;
    const int fr = lane & 15, fg = lane >> 4;
    const int brow = by * 256;
    const int bcol = bx * 256;

    // staging map: 1024 chunks per operand, ONE per thread
    size_t a_g, b_g;
    int    l_of;
    {
        int q = tid;
        int p = q >> 3, c8 = q & 7, c8l = c8 ^ (p & 7);
        int r = 2 * p + (c8l >> 2);
        int k = (c8l & 3) * 8;
        a_g = (size_t)(brow + r) * K_DIM + k;
        int wrow = bcol + r; if (wrow >= CLS) wrow = CLS - 1;   // clamp pad
        b_g = (size_t)wrow * K_DIM + k;
        l_of = q * 8;                       // ushorts
    }

    // fragment-read offsets (verified layout); per-wave 64x64 output
    int afoff[4], bfoff[4];
#pragma unroll
    for (int m = 0; m < 4; ++m) {
        int row = wr * 64 + m * 16 + fr;
        int p = row >> 1;
        int c = (((row & 1) << 2) | fg) ^ (p & 7);
        afoff[m] = (p * 8 + c) * 8;
    }
#pragma unroll
    for (int n = 0; n < 4; ++n) {
        int row = wc * 64 + n * 16 + fr;
        int p = row >> 1;
        int c = (((row & 1) << 2) | fg) ^ (p & 7);
        bfoff[n] = (p * 8 + c) * 8;
    }

    floatx4 acc[4][4];
#pragma unroll
    for (int m = 0; m < 4; ++m)
#pragma unroll
        for (int n = 0; n < 4; ++n)
            acc[m][n] = (floatx4){0.f, 0.f, 0.f, 0.f};

    float4 ga[2], gb[2];                    // staged fp32 (one chunk each)

#define LOADT(t_) {                                                           \
    const size_t kb_ = (size_t)(t_) * 32;                                     \
    ga[0] = *(const float4*)(A + a_g + kb_);                                  \
    ga[1] = *(const float4*)(A + a_g + kb_ + 4);                              \
    gb[0] = *(const float4*)(B + b_g + kb_);                                  \
    gb[1] = *(const float4*)(B + b_g + kb_ + 4);                              \
}

#define CVTW(sl_) {                                                           \
    ushort8 ta, tb;                                                           \
    _Pragma("unroll")                                                         \
    for (int j = 0; j < 4; ++j) {                                             \
        ta[j]     = f2bfr(((const float*)&ga[0])[j]);                         \
        ta[j + 4] = f2bfr(((const float*)&ga[1])[j]);                         \
        tb[j]     = f2bfr(((const float*)&gb[0])[j]);                         \
        tb[j + 4] = f2bfr(((const float*)&gb[1])[j]);                         \
    }                                                                         \
    *(ushort8*)&As[sl_][l_of] = ta;                                           \
    *(ushort8*)&Bs[sl_][l_of] = tb;                                           \
}

#define COMPUTE(t_) {                                                         \
    const ushort* asl = &As[(t_) & 3][0];                                     \
    const ushort* bsl = &Bs[(t_) & 3][0];                                     \
    short8 af[4], bf[4];                                                      \
    _Pragma("unroll")                                                         \
    for (int m = 0; m < 4; ++m) af[m] = *(const short8*)(asl + afoff[m]);     \
    _Pragma("unroll")                                                         \
    for (int n = 0; n < 4; ++n) bf[n] = *(const short8*)(bsl + bfoff[n]);     \
    PRIO1;                                                                    \
    _Pragma("unroll")                                                         \
    for (int m = 0; m < 4; ++m)                                               \
        _Pragma("unroll")                                                     \
        for (int n = 0; n < 4; ++n)                                           \
            acc[m][n] = __builtin_amdgcn_mfma_f32_16x16x32_bf16(              \
                af[m], bf[n], acc[m][n], 0, 0, 0);                            \
    PRIO0;                                                                    \
}

    // prologue: tiles 0,1 staged to slots 0,1; loads of tile 2 in flight
    LOADT(0)
    CVTW(0)
    LOADT(1)
    CVTW(1)
    LOADT(2)
    SB0; LGKM0; BARX; SB0;

#pragma unroll 1
    for (int s = 0; s < NT / 2; ++s) {
        const int t0 = 2 * s, t1 = 2 * s + 1;
        COMPUTE(t0)
        if (t0 + 2 < NT) CVTW((t0 + 2) & 3)     // consumes last window's loads
        if (t0 + 3 < NT) LOADT(t0 + 3)
        COMPUTE(t1)
        if (t1 + 2 < NT) CVTW((t1 + 2) & 3)     // consumes LOADT(t0+3)
        if (t1 + 3 < NT) LOADT(t1 + 3)
        SB0; LGKM0; BARX; SB0;                  // ONE barrier per 2 tiles
    }

    // epilogue: alpha = softplus(z + bias) + 1, predicated on col < 1000
#pragma unroll
    for (int n = 0; n < 4; ++n) {
        int col = bcol + wc * 64 + n * 16 + fr;
        if (col >= CLS) continue;
        float bv = bias[col];
#pragma unroll
        for (int m = 0; m < 4; ++m) {
#pragma unroll
            for (int j = 0; j < 4; ++j) {
                int row = brow + wr * 64 + m * 16 + fg * 4 + j;
                float z = acc[m][n][j] + bv;
                out[(size_t)row * CLS + col] = softplus_fast(z) + 1.f;
            }
        }
    }
}

// ---------------- DS combine: one wave per row, shuffle-xor reduce ----------

__global__ __launch_bounds__(256)
void ds_combine(const float* __restrict__ AX, const float* __restrict__ AY,
                float* __restrict__ out)
{
    const int row = blockIdx.x * 4 + (threadIdx.x >> 6);
    const int l = threadIdx.x & 63;
    const float* ax = AX + (size_t)row * CLS;
    const float* ay = AY + (size_t)row * CLS;

    float4 vx[4], vy[4];
    float sx = 0.f, sy = 0.f, sp = 0.f;
#pragma unroll
    for (int c = 0; c < 4; ++c) {
        int idx = l + c * 64;
        if (idx < CLS / 4) {
            vx[c] = *(const float4*)(ax + idx * 4);
            vy[c] = *(const float4*)(ay + idx * 4);
            const float* px = (const float*)&vx[c];
            const float* py = (const float*)&vy[c];
#pragma unroll
            for (int j = 0; j < 4; ++j) {
                sx += px[j]; sy += py[j];
                sp += (px[j] - 1.f) * (py[j] - 1.f);
            }
        }
    }
#pragma unroll
    for (int off = 1; off < 64; off <<= 1) {
        sx += __shfl_xor(sx, off);
        sy += __shfl_xor(sy, off);
        sp += __shfl_xor(sp, off);
    }
    const float S1 = sx, S2 = sy, P = sp;
    const float i1 = 1.f / S1, i2 = 1.f / S2;
    const float u1 = (float)CLS * i1, u2 = (float)CLS * i2;
    const float sb1 = (S1 - (float)CLS) * i1;
    const float sb2 = (S2 - (float)CLS) * i2;
    const float conf = sb1 * sb2 - P * i1 * i2;
    const float denom = 1.f - conf;
    const float idenom = 1.f / denom;
    const float Sa = (float)CLS * denom / (u1 * u2);

#pragma unroll
    for (int c = 0; c < 4; ++c) {
        int idx = l + c * 64;
        if (idx < CLS / 4) {
            float4 vo;
            const float* px = (const float*)&vx[c];
            const float* py = (const float*)&vy[c];
            float* po = (float*)&vo;
#pragma unroll
            for (int j = 0; j < 4; ++j) {
                float b1 = (px[j] - 1.f) * i1;
                float b2 = (py[j] - 1.f) * i2;
                float ba = (b1 * b2 + b1 * u2 + b2 * u1) * idenom;
                po[j] = ba * Sa + 1.f;
            }
            *(float4*)(out + (size_t)row * CLS + idx * 4) = vo;
        }
    }
}

extern "C" void kernel_launch(void* const* d_in, const int* in_sizes, int n_in,
                              void* d_out, int out_size, void* d_ws, size_t ws_size,
                              hipStream_t stream) {
    const float* x  = (const float*)d_in[0];
    const float* y  = (const float*)d_in[1];
    const float* Wx = (const float*)d_in[2];
    const float* bx = (const float*)d_in[3];
    const float* Wy = (const float*)d_in[4];
    const float* by = (const float*)d_in[5];
    float* out = (float*)d_out;
    float* ax = out + (size_t)BATCH_N * CLS;
    float* ay = ax  + (size_t)BATCH_N * CLS;

    gemm_fused<<<dim3(4, 32, 2), 1024, 0, stream>>>(
        x, y, Wx, Wy, bx, by, ax, ay);
    ds_combine<<<BATCH_N / 4, 256, 0, stream>>>(ax, ay, out);
}